// Round 1
// 531.636 us; speedup vs baseline: 1.1618x; 1.1618x over previous
//
#include <hip/hip_runtime.h>
#include <math.h>

#define N 8192
#define NW 128          // 64-bit mask words per row
#define FIN 29
#define FH 8
#define NH 4
#define ALPHA 0.2f
#define LOG2E 1.4426950408889634f
#define JS 4            // layer-1 j-splits
#define JRR (N / JS)    // 2048
#define JS2 4

typedef unsigned long long ull;
typedef unsigned short u16;
typedef __attribute__((ext_vector_type(8))) short bf16x8;
typedef __attribute__((ext_vector_type(4))) float f32x4;

__device__ inline unsigned bf16rn(float f) {
    unsigned u = __float_as_uint(f);
    return (u + 0x7fffu + ((u >> 16) & 1u)) >> 16;
}
// monotone float <-> unsigned encoding for atomicMax
__device__ inline unsigned fenc(float x) {
    unsigned u = __float_as_uint(x);
    return (u & 0x80000000u) ? ~u : (u | 0x80000000u);
}
__device__ inline float fdec(unsigned e) {
    return __uint_as_float((e & 0x80000000u) ? (e & 0x7fffffffu) : ~e);
}

// ---------------- K0: pack adj (256 MB int32) into bitmask (8 MB) ----------------
// bit of word w=(i*4+wave), lane  <->  element i*256 + wave*64 + lane = i*256+tid.
__global__ void k0_pack(const int* __restrict__ adj, ull* __restrict__ mask,
                        unsigned* __restrict__ amax) {
    int row = blockIdx.x;
    int tid = threadIdx.x;
    int lane = tid & 63;
    int wave = tid >> 6;
    if (row == 0 && tid < 8) amax[tid] = 0u;   // init atomic-max slots
    const int* rp = adj + (size_t)row * N;
#pragma unroll 8
    for (int i = 0; i < 32; i++) {
        int a = rp[i * 256 + tid];
        ull b = __ballot(a > 0);
        if (lane == 0) mask[(size_t)row * NW + i * 4 + wave] = b;
    }
}

// ---------------- K1: per-node features ----------------
// Outputs (all in LOG2E units where exponential):
//   e2[h][j]  = float2( exp2(f2L), exp2(ALPHA*f2L) )   -- per-column exp factors
//   Ht[h][c][j] bf16 transposed features, c=0..7 = h_c, c=8 = 1.0 (MFMA B operand
//               with built-in ones column -> softmax denominator for free)
//   f1a[j*4+h] = f1L ; amax[h] = max_j f2L
__global__ __launch_bounds__(64) void k1_feat(
    const float* __restrict__ x, const float* __restrict__ Wh,
    const float* __restrict__ ah,
    float2* __restrict__ e2, u16* __restrict__ Ht,
    float* __restrict__ f1a, unsigned* __restrict__ amax) {
    __shared__ float sW[NH * FIN * FH];
    __shared__ float sa[NH * 2 * FH];
    int tid = threadIdx.x;
    for (int i = tid; i < NH * FIN * FH; i += 64) sW[i] = Wh[i];
    for (int i = tid; i < NH * 2 * FH; i += 64) sa[i] = ah[i];
    __syncthreads();
    int node = blockIdx.x * 64 + tid;   // N % 64 == 0
    float xr[FIN];
#pragma unroll
    for (int f = 0; f < FIN; f++) xr[f] = x[node * FIN + f];
    float f2v[NH];
#pragma unroll
    for (int h = 0; h < NH; h++) {
        float hv[FH];
#pragma unroll
        for (int k = 0; k < FH; k++) {
            float s = 0.f;
#pragma unroll
            for (int f = 0; f < FIN; f++) s += xr[f] * sW[(h * FIN + f) * FH + k];
            hv[k] = s;
        }
        float f1 = 0.f, f2 = 0.f;
#pragma unroll
        for (int k = 0; k < FH; k++) {
            f1 += hv[k] * sa[h * 16 + k];
            f2 += hv[k] * sa[h * 16 + 8 + k];
        }
        float f1L = f1 * LOG2E, f2L = f2 * LOG2E;
        f2v[h] = f2L;
        f1a[node * 4 + h] = f1L;
        e2[h * N + node] = make_float2(__builtin_amdgcn_exp2f(f2L),
                                       __builtin_amdgcn_exp2f(ALPHA * f2L));
#pragma unroll
        for (int k = 0; k < FH; k++)
            Ht[(size_t)(h * 9 + k) * N + node] = (u16)bf16rn(hv[k]);
        Ht[(size_t)(h * 9 + 8) * N + node] = 0x3F80u;   // 1.0 bf16 (denominator col)
    }
    // fused per-head global max of f2L
#pragma unroll
    for (int h = 0; h < NH; h++) {
        float v = f2v[h];
        for (int off = 32; off > 0; off >>= 1) v = fmaxf(v, __shfl_xor(v, off, 64));
        if (tid == 0) atomicMax(&amax[h], fenc(v));
    }
}

// ---------------- K3: layer-1 attention via MFMA ----------------
// w_ij = exp2(lrelu(f1+f2) - m) = max(E1p_i*E2p_j, E1n_i*E2n_j)  (exp2 monotone)
// -> no transcendentals in inner loop; 9-wide accumulation on the matrix pipe.
// Block: 256 thr = 4 waves; wave = one 16-row m-tile; block = (rowblk64, js, h).
// A-frag: lane row = lane&15, k = (lane>>4)*8+e (w packed to bf16 via cvt_pk).
// B-frag: lane col c = lane&15, 16B load from Ht[h][c][j] (c>8 lanes read garbage
//         inside workspace -> unused output cols, harmless).
// D: col = lane&15, row = (lane>>4)*4 + reg -> float4 store to part1.
__global__ __launch_bounds__(256) void k3_attn1(
    const ull* __restrict__ mask, const float2* __restrict__ e2,
    const u16* __restrict__ Ht, const float* __restrict__ f1a,
    const unsigned* __restrict__ amax, float* __restrict__ part1) {
    __shared__ __align__(16) float2 sE2[JRR];   // 16 KB
    int tid = threadIdx.x;
    int lane = tid & 63;
    int wave = tid >> 6;
    int h = blockIdx.x & 3;
    int js = (blockIdx.x >> 2) & 3;
    int rowblk = blockIdx.x >> 4;        // 0..127
    int jbase = js * JRR;

    {   // stage E2 pairs for this (head, j-range) once; only barrier in kernel
        const float4* src = (const float4*)(e2 + (size_t)h * N + jbase);
        float4* dst = (float4*)sE2;
#pragma unroll
        for (int i = 0; i < (JRR / 2) / 256; i++)   // 4 iters
            dst[tid + i * 256] = src[tid + i * 256];
    }

    int c = lane & 15;                   // B col / A row selector
    int kb = lane >> 4;                  // k-group 0..3
    int sh = kb * 8;
    int r = rowblk * 64 + wave * 16 + c; // this lane's A row

    float mfL = fdec(amax[h]);
    float f1 = f1a[r * 4 + h];
    float v = f1 + mfL, m = fmaxf(v, ALPHA * v);
    float e1p = __builtin_amdgcn_exp2f(f1 - m);
    float e1n = __builtin_amdgcn_exp2f(ALPHA * f1 - m);

    const ull* mrow = mask + (size_t)r * NW + (jbase >> 6);
    const char* bbase = (const char*)(Ht + ((size_t)(h * 9 + c) * N + jbase + kb * 8));

    f32x4 acc = {0.f, 0.f, 0.f, 0.f};
    __syncthreads();

    for (int t = 0; t < JRR / 64; t++) {   // 32
        ull mw = mrow[t];
        unsigned mlo = (unsigned)mw;
        unsigned mhi = (unsigned)(mw >> 32);
#pragma unroll
        for (int hf = 0; hf < 2; hf++) {
            unsigned sw = (hf ? mhi : mlo) >> sh;
            const float4* qp = (const float4*)(sE2 + t * 64 + hf * 32 + kb * 8);
            float4 q0 = qp[0], q1 = qp[1], q2 = qp[2], q3 = qp[3];
            float w0 = fmaxf(e1p * q0.x, e1n * q0.y);
            float w1 = fmaxf(e1p * q0.z, e1n * q0.w);
            float w2 = fmaxf(e1p * q1.x, e1n * q1.y);
            float w3 = fmaxf(e1p * q1.z, e1n * q1.w);
            float w4 = fmaxf(e1p * q2.x, e1n * q2.y);
            float w5 = fmaxf(e1p * q2.z, e1n * q2.w);
            float w6 = fmaxf(e1p * q3.x, e1n * q3.y);
            float w7 = fmaxf(e1p * q3.z, e1n * q3.w);
            w0 = (sw & 1u)   ? w0 : 0.f;
            w1 = (sw & 2u)   ? w1 : 0.f;
            w2 = (sw & 4u)   ? w2 : 0.f;
            w3 = (sw & 8u)   ? w3 : 0.f;
            w4 = (sw & 16u)  ? w4 : 0.f;
            w5 = (sw & 32u)  ? w5 : 0.f;
            w6 = (sw & 64u)  ? w6 : 0.f;
            w7 = (sw & 128u) ? w7 : 0.f;
            uint4 ap;
            asm("v_cvt_pk_bf16_f32 %0, %1, %2" : "=v"(ap.x) : "v"(w0), "v"(w1));
            asm("v_cvt_pk_bf16_f32 %0, %1, %2" : "=v"(ap.y) : "v"(w2), "v"(w3));
            asm("v_cvt_pk_bf16_f32 %0, %1, %2" : "=v"(ap.z) : "v"(w4), "v"(w5));
            asm("v_cvt_pk_bf16_f32 %0, %1, %2" : "=v"(ap.w) : "v"(w6), "v"(w7));
            uint4 bp = *(const uint4*)(bbase + t * 128 + hf * 64);
            acc = __builtin_amdgcn_mfma_f32_16x16x32_bf16(
                __builtin_bit_cast(bf16x8, ap), __builtin_bit_cast(bf16x8, bp),
                acc, 0, 0, 0);
        }
    }
    if (c <= 8) {   // cols 0..7 = features, 8 = denominator
        int rowout = rowblk * 64 + wave * 16 + kb * 4;
        float* dst = part1 + (size_t)(js * 36 + h * 9 + c) * N + rowout;
        *(float4*)dst = make_float4(acc[0], acc[1], acc[2], acc[3]);
    }
}

// ---------------- K3b: finalize layer 1 + layer-2 features + fused layer-2 max ----------------
__global__ void k3b_final(const float* __restrict__ part1, const float* __restrict__ Wo,
                          const float* __restrict__ ao,
                          float4* __restrict__ rec2, float* __restrict__ f1b,
                          unsigned* __restrict__ amax) {
    __shared__ float sW[64];
    __shared__ float sa[4];
    int tid = threadIdx.x;
    if (tid < 64) sW[tid] = Wo[tid];
    if (tid < 4) sa[tid] = ao[tid];
    __syncthreads();
    int row = blockIdx.x * 256 + tid;
    float hv[32];
#pragma unroll
    for (int h = 0; h < NH; h++) {
        float s[9];
#pragma unroll
        for (int cc = 0; cc < 9; cc++) {
            float acc = 0.f;
#pragma unroll
            for (int js = 0; js < JS; js++)
                acc += part1[(size_t)(js * 36 + h * 9 + cc) * N + row];
            s[cc] = acc;
        }
        float inv = 1.f / s[8];
#pragma unroll
        for (int k = 0; k < FH; k++) {
            float o = s[k] * inv;
            hv[h * 8 + k] = (o > 0.f) ? o : expm1f(o);
        }
    }
    float h0 = 0.f, h1 = 0.f;
#pragma unroll
    for (int i = 0; i < 32; i++) {
        h0 = fmaf(hv[i], sW[i * 2 + 0], h0);
        h1 = fmaf(hv[i], sW[i * 2 + 1], h1);
    }
    float f1 = (h0 * sa[0] + h1 * sa[1]) * LOG2E;
    float f2 = (h0 * sa[2] + h1 * sa[3]) * LOG2E;
    // rec2 carries the exp-factorized per-column pair for layer 2
    rec2[row] = make_float4(__builtin_amdgcn_exp2f(f2), h0, h1,
                            __builtin_amdgcn_exp2f(ALPHA * f2));
    f1b[row] = f1;
    float vmax = f2;
    for (int off = 32; off > 0; off >>= 1) vmax = fmaxf(vmax, __shfl_xor(vmax, off, 64));
    if ((tid & 63) == 0) atomicMax(&amax[4], fenc(vmax));
}

// ---------------- K6: layer-2 attention partials — exp-factorized, no LDS ----------------
__global__ __launch_bounds__(256) void k6_attn2(
    const ull* __restrict__ mask, const float4* __restrict__ rec2,
    const float* __restrict__ f1b, const unsigned* __restrict__ amax,
    float* __restrict__ part2) {
    int tid = threadIdx.x;
    int lane = tid & 63;
    int wave = tid >> 6;
    int blk = blockIdx.x >> 2;
    int js = blockIdx.x & 3;
    int rbase = blk * 16 + wave * 4;
    const int JR = N / JS2;   // 2048
    int jbase = js * JR;

    float mb = fdec(amax[4]);
    float e1p[4], e1n[4];
#pragma unroll
    for (int i = 0; i < 4; i++) {
        float f1 = f1b[rbase + i];
        float v = f1 + mb, m = fmaxf(v, ALPHA * v);
        e1p[i] = __builtin_amdgcn_exp2f(f1 - m);
        e1n[i] = __builtin_amdgcn_exp2f(ALPHA * f1 - m);
    }
    float a0[4] = {0.f, 0.f, 0.f, 0.f};
    float a1[4] = {0.f, 0.f, 0.f, 0.f};
    float dd[4] = {0.f, 0.f, 0.f, 0.f};
    const ull* mr[4];
#pragma unroll
    for (int i = 0; i < 4; i++) mr[i] = mask + (size_t)(rbase + i) * NW;

    int wb = jbase >> 6;
#pragma unroll 4
    for (int s = 0; s < JR / 64; s++) {   // 32
        float4 q = rec2[jbase + s * 64 + lane];
#pragma unroll
        for (int i = 0; i < 4; i++) {
            ull mw = mr[i][wb + s];
            float w = fmaxf(e1p[i] * q.x, e1n[i] * q.w);
            w = ((mw >> lane) & 1ull) ? w : 0.f;
            a0[i] = fmaf(w, q.y, a0[i]);
            a1[i] = fmaf(w, q.z, a1[i]);
            dd[i] += w;
        }
    }
#pragma unroll
    for (int i = 0; i < 4; i++) {
        for (int off = 32; off > 0; off >>= 1) {
            a0[i] += __shfl_xor(a0[i], off, 64);
            a1[i] += __shfl_xor(a1[i], off, 64);
            dd[i] += __shfl_xor(dd[i], off, 64);
        }
    }
    if (lane == 0) {
#pragma unroll
        for (int i = 0; i < 4; i++) {
            int row = rbase + i;
            part2[(js * 3 + 0) * N + row] = a0[i];
            part2[(js * 3 + 1) * N + row] = a1[i];
            part2[(js * 3 + 2) * N + row] = dd[i];
        }
    }
}

// ---------------- K6b: finalize layer 2 + log_softmax ----------------
__global__ void k6b_final(const float* __restrict__ part2, float* __restrict__ out) {
    int row = blockIdx.x * 256 + threadIdx.x;
    float s0 = 0.f, s1 = 0.f, d = 0.f;
#pragma unroll
    for (int js = 0; js < JS2; js++) {
        s0 += part2[(js * 3 + 0) * N + row];
        s1 += part2[(js * 3 + 1) * N + row];
        d  += part2[(js * 3 + 2) * N + row];
    }
    float inv = 1.f / d;
    float e0 = s0 * inv, e1 = s1 * inv;
    e0 = (e0 > 0.f) ? e0 : expm1f(e0);
    e1 = (e1 > 0.f) ? e1 : expm1f(e1);
    float mx = fmaxf(e0, e1);
    float lse = mx + logf(expf(e0 - mx) + expf(e1 - mx));
    ((float2*)out)[row] = make_float2(e0 - lse, e1 - lse);
}

extern "C" void kernel_launch(void* const* d_in, const int* in_sizes, int n_in,
                              void* d_out, int out_size, void* d_ws, size_t ws_size,
                              hipStream_t stream) {
    const float* x   = (const float*)d_in[0];
    const int*   adj = (const int*)d_in[1];
    const float* Wh  = (const float*)d_in[2];
    const float* ah  = (const float*)d_in[3];
    const float* Wo  = (const float*)d_in[4];
    const float* ao  = (const float*)d_in[5];
    float* out = (float*)d_out;
    float* ws = (float*)d_ws;

    // workspace layout (float offsets)
    ull*      mask  = (ull*)ws;                       // 8 MB = 2097152 floats
    float2*   e2    = (float2*)(ws + 2097152);        // 4*N float2 = 65536 floats
    u16*      Ht    = (u16*)(ws + 2162688);           // 4*9*N u16 = 147456 floats
    float*    f1a   = ws + 2310144;                   // 4*N
    float*    part1 = ws + 2342912;                   // 4*36*N = 1179648
    float4*   rec2  = (float4*)(ws + 3522560);        // N float4
    float*    f1b   = ws + 3555328;                   // N
    float*    part2 = ws + 3563520;                   // 12*N = 98304
    unsigned* amax  = (unsigned*)(ws + 3661824);      // 8 slots (0..3 heads, 4 layer2)

    k0_pack<<<N, 256, 0, stream>>>(adj, mask, amax);
    k1_feat<<<N / 64, 64, 0, stream>>>(x, Wh, ah, e2, Ht, f1a, amax);
    k3_attn1<<<(N / 64) * JS * NH, 256, 0, stream>>>(mask, e2, Ht, f1a, amax, part1);
    k3b_final<<<N / 256, 256, 0, stream>>>(part1, Wo, ao, rec2, f1b, amax);
    k6_attn2<<<(N / 16) * JS2, 256, 0, stream>>>(mask, rec2, f1b, amax, part2);
    k6b_final<<<N / 256, 256, 0, stream>>>(part2, out);
}

// Round 2
// 503.880 us; speedup vs baseline: 1.2258x; 1.0551x over previous
//
#include <hip/hip_runtime.h>
#include <math.h>

#define N 8192
#define NW 128          // 64-bit mask words per row
#define FIN 29
#define FH 8
#define NH 4
#define ALPHA 0.2f
#define LOG2E 1.4426950408889634f
#define JS 4            // layer-1 j-splits
#define JRR (N / JS)    // 2048
#define JS2 4

typedef unsigned long long ull;
typedef unsigned short u16;
typedef __attribute__((ext_vector_type(8))) short bf16x8;
typedef __attribute__((ext_vector_type(4))) float f32x4;

__device__ inline unsigned bf16rn(float f) {
    unsigned u = __float_as_uint(f);
    return (u + 0x7fffu + ((u >> 16) & 1u)) >> 16;
}
// monotone float <-> unsigned encoding for atomicMax
__device__ inline unsigned fenc(float x) {
    unsigned u = __float_as_uint(x);
    return (u & 0x80000000u) ? ~u : (u | 0x80000000u);
}
__device__ inline float fdec(unsigned e) {
    return __uint_as_float((e & 0x80000000u) ? (e & 0x7fffffffu) : ~e);
}

// ---------------- K0: pack adj (256 MB int32) into bitmask (8 MB) ----------------
// HBM-bound floor ~42 us (268 MB read). bit of word w=(i*4+wave), lane
//   <-> element i*256 + wave*64 + lane = i*256+tid.
__global__ void k0_pack(const int* __restrict__ adj, ull* __restrict__ mask,
                        unsigned* __restrict__ amax) {
    int row = blockIdx.x;
    int tid = threadIdx.x;
    int lane = tid & 63;
    int wave = tid >> 6;
    if (row == 0 && tid < 8) amax[tid] = 0u;   // init atomic-max slots
    const int* rp = adj + (size_t)row * N;
#pragma unroll 8
    for (int i = 0; i < 32; i++) {
        int a = rp[i * 256 + tid];
        ull b = __ballot(a > 0);
        if (lane == 0) mask[(size_t)row * NW + i * 4 + wave] = b;
    }
}

// ---------------- K1: per-node features, one thread per (node, head) ----------------
// Outputs:
//   e2[h][j]   = float2( exp2(f2L), exp2(ALPHA*f2L) )   -- per-column exp factors
//   Bpk        = B operand pre-packed in MFMA fragment order:
//                u16 index ((((h*4+js)*32+t)*2+hf)*64 + kb*16+c)*8 + e
//                holds bf16 H[j][c] for j = js*2048+t*64+hf*32+kb*8+e
//                (c=8 -> 1.0 denominator column, c=9..15 -> 0)
//                => k3's B-load is one fully coalesced dwordx4 per wave. No gathers.
//   f1a[j*4+h] = f1L ; amax[h] = max_j f2L
__global__ __launch_bounds__(256) void k1_feat(
    const float* __restrict__ x, const float* __restrict__ Wh,
    const float* __restrict__ ah,
    float2* __restrict__ e2, u16* __restrict__ Bpk,
    float* __restrict__ f1a, unsigned* __restrict__ amax) {
    __shared__ float sx[64 * FIN];      // 7.4 KB
    __shared__ float sW[NH * FIN * FH];
    __shared__ float sa[NH * 2 * FH];
    int tid = threadIdx.x;
    for (int i = tid; i < NH * FIN * FH; i += 256) sW[i] = Wh[i];
    for (int i = tid; i < NH * 2 * FH; i += 256) sa[i] = ah[i];
    for (int i = tid; i < 64 * FIN; i += 256) sx[i] = x[(size_t)blockIdx.x * 64 * FIN + i];
    __syncthreads();
    int h = tid & 3;
    int nl = tid >> 2;                  // node-local 0..63
    int node = blockIdx.x * 64 + nl;
    float hv[FH];
#pragma unroll
    for (int k = 0; k < FH; k++) {
        float s = 0.f;
#pragma unroll
        for (int f = 0; f < FIN; f++) s += sx[nl * FIN + f] * sW[(h * FIN + f) * FH + k];
        hv[k] = s;
    }
    float f1 = 0.f, f2 = 0.f;
#pragma unroll
    for (int k = 0; k < FH; k++) {
        f1 += hv[k] * sa[h * 16 + k];
        f2 += hv[k] * sa[h * 16 + 8 + k];
    }
    float f1L = f1 * LOG2E, f2L = f2 * LOG2E;
    f1a[node * 4 + h] = f1L;
    e2[(size_t)h * N + node] = make_float2(__builtin_amdgcn_exp2f(f2L),
                                           __builtin_amdgcn_exp2f(ALPHA * f2L));
    // fragment-order pack
    int js = node >> 11;
    int t  = (node >> 6) & 31;
    int hfl = (node >> 5) & 1;
    int kb = (node >> 3) & 3;
    int e  = node & 7;
    u16* dst = Bpk + ((size_t)(((h * 4 + js) * 32 + t) * 2 + hfl)) * 512 + e;
#pragma unroll
    for (int cc = 0; cc < 16; cc++) {
        u16 v = (cc < FH) ? (u16)bf16rn(hv[cc])
                          : ((cc == 8) ? (u16)0x3F80u : (u16)0);
        dst[(kb * 16 + cc) * 8] = v;
    }
    // per-head global max of f2L (offs 4..32 keep head classes separate)
    float v = f2L;
    for (int off = 4; off < 64; off <<= 1) v = fmaxf(v, __shfl_xor(v, off, 64));
    if ((tid & 63) < 4) atomicMax(&amax[tid & 3], fenc(v));
}

// ---------------- K3: layer-1 attention via MFMA, zero barriers, m=2 row-tiles ----------------
// w_ij = exp2(lrelu(f1+f2) - m) = max(E1p_i*E2p_j, E1n_i*E2n_j)  (exp2 monotone)
// Block: 256 thr = 4 waves; each wave owns TWO 16-row tiles (r0, r0+64) sharing
// the same B fragment and e2 loads. B comes coalesced from Bpk; e2 via L2
// broadcast loads (16-lane groups share addresses). Only remaining gather is
// the per-lane mask word (16 rows x 8 B, 2 per t).
__global__ __launch_bounds__(256, 4) void k3_attn1(
    const ull* __restrict__ mask, const float2* __restrict__ e2,
    const uint4* __restrict__ Bpk, const float* __restrict__ f1a,
    const unsigned* __restrict__ amax, float* __restrict__ part1) {
    int tid = threadIdx.x;
    int lane = tid & 63;
    int wave = tid >> 6;
    int h = blockIdx.x & 3;
    int js = (blockIdx.x >> 2) & 3;
    int rowblk = blockIdx.x >> 4;        // 0..63
    int jbase = js * JRR;

    int c = lane & 15;                   // B col / A row selector
    int kb = lane >> 4;                  // k-group 0..3
    int sh = kb * 8;
    int r0 = rowblk * 128 + wave * 16 + c;
    int r1 = r0 + 64;

    float mfL = fdec(amax[h]);
    float f1 = f1a[r0 * 4 + h];
    float vv = f1 + mfL, mm = fmaxf(vv, ALPHA * vv);
    float e1p0 = __builtin_amdgcn_exp2f(f1 - mm);
    float e1n0 = __builtin_amdgcn_exp2f(ALPHA * f1 - mm);
    f1 = f1a[r1 * 4 + h];
    vv = f1 + mfL; mm = fmaxf(vv, ALPHA * vv);
    float e1p1 = __builtin_amdgcn_exp2f(f1 - mm);
    float e1n1 = __builtin_amdgcn_exp2f(ALPHA * f1 - mm);

    const ull* mr0 = mask + (size_t)r0 * NW + (jbase >> 6);
    const ull* mr1 = mask + (size_t)r1 * NW + (jbase >> 6);
    const float2* e2h = e2 + (size_t)h * N + jbase + kb * 8;
    const uint4* bp0 = Bpk + (size_t)(h * 4 + js) * 4096 + lane;

    f32x4 acc0 = {0.f, 0.f, 0.f, 0.f};
    f32x4 acc1 = {0.f, 0.f, 0.f, 0.f};

    for (int t = 0; t < JRR / 64; t++) {   // 32
        ull mw0 = mr0[t];
        ull mw1 = mr1[t];
#pragma unroll
        for (int hf = 0; hf < 2; hf++) {
            const float4* qp = (const float4*)(e2h + t * 64 + hf * 32);
            float4 q0 = qp[0], q1 = qp[1], q2 = qp[2], q3 = qp[3];
            uint4 bp = bp0[(t * 2 + hf) * 64];
            unsigned sw0 = ((unsigned)(mw0 >> (hf * 32))) >> sh;
            unsigned sw1 = ((unsigned)(mw1 >> (hf * 32))) >> sh;
            {   // ---- row tile 0
                float w0 = fmaxf(e1p0 * q0.x, e1n0 * q0.y);
                float w1 = fmaxf(e1p0 * q0.z, e1n0 * q0.w);
                float w2 = fmaxf(e1p0 * q1.x, e1n0 * q1.y);
                float w3 = fmaxf(e1p0 * q1.z, e1n0 * q1.w);
                float w4 = fmaxf(e1p0 * q2.x, e1n0 * q2.y);
                float w5 = fmaxf(e1p0 * q2.z, e1n0 * q2.w);
                float w6 = fmaxf(e1p0 * q3.x, e1n0 * q3.y);
                float w7 = fmaxf(e1p0 * q3.z, e1n0 * q3.w);
                w0 = (sw0 & 1u)   ? w0 : 0.f;
                w1 = (sw0 & 2u)   ? w1 : 0.f;
                w2 = (sw0 & 4u)   ? w2 : 0.f;
                w3 = (sw0 & 8u)   ? w3 : 0.f;
                w4 = (sw0 & 16u)  ? w4 : 0.f;
                w5 = (sw0 & 32u)  ? w5 : 0.f;
                w6 = (sw0 & 64u)  ? w6 : 0.f;
                w7 = (sw0 & 128u) ? w7 : 0.f;
                uint4 ap;
                asm("v_cvt_pk_bf16_f32 %0, %1, %2" : "=v"(ap.x) : "v"(w0), "v"(w1));
                asm("v_cvt_pk_bf16_f32 %0, %1, %2" : "=v"(ap.y) : "v"(w2), "v"(w3));
                asm("v_cvt_pk_bf16_f32 %0, %1, %2" : "=v"(ap.z) : "v"(w4), "v"(w5));
                asm("v_cvt_pk_bf16_f32 %0, %1, %2" : "=v"(ap.w) : "v"(w6), "v"(w7));
                acc0 = __builtin_amdgcn_mfma_f32_16x16x32_bf16(
                    __builtin_bit_cast(bf16x8, ap), __builtin_bit_cast(bf16x8, bp),
                    acc0, 0, 0, 0);
            }
            {   // ---- row tile 1 (reuses q*, bp)
                float w0 = fmaxf(e1p1 * q0.x, e1n1 * q0.y);
                float w1 = fmaxf(e1p1 * q0.z, e1n1 * q0.w);
                float w2 = fmaxf(e1p1 * q1.x, e1n1 * q1.y);
                float w3 = fmaxf(e1p1 * q1.z, e1n1 * q1.w);
                float w4 = fmaxf(e1p1 * q2.x, e1n1 * q2.y);
                float w5 = fmaxf(e1p1 * q2.z, e1n1 * q2.w);
                float w6 = fmaxf(e1p1 * q3.x, e1n1 * q3.y);
                float w7 = fmaxf(e1p1 * q3.z, e1n1 * q3.w);
                w0 = (sw1 & 1u)   ? w0 : 0.f;
                w1 = (sw1 & 2u)   ? w1 : 0.f;
                w2 = (sw1 & 4u)   ? w2 : 0.f;
                w3 = (sw1 & 8u)   ? w3 : 0.f;
                w4 = (sw1 & 16u)  ? w4 : 0.f;
                w5 = (sw1 & 32u)  ? w5 : 0.f;
                w6 = (sw1 & 64u)  ? w6 : 0.f;
                w7 = (sw1 & 128u) ? w7 : 0.f;
                uint4 ap;
                asm("v_cvt_pk_bf16_f32 %0, %1, %2" : "=v"(ap.x) : "v"(w0), "v"(w1));
                asm("v_cvt_pk_bf16_f32 %0, %1, %2" : "=v"(ap.y) : "v"(w2), "v"(w3));
                asm("v_cvt_pk_bf16_f32 %0, %1, %2" : "=v"(ap.z) : "v"(w4), "v"(w5));
                asm("v_cvt_pk_bf16_f32 %0, %1, %2" : "=v"(ap.w) : "v"(w6), "v"(w7));
                acc1 = __builtin_amdgcn_mfma_f32_16x16x32_bf16(
                    __builtin_bit_cast(bf16x8, ap), __builtin_bit_cast(bf16x8, bp),
                    acc1, 0, 0, 0);
            }
        }
    }
    if (c <= 8) {   // cols 0..7 = features, 8 = denominator
        int ro = rowblk * 128 + wave * 16 + kb * 4;
        float* dst = part1 + (size_t)(js * 36 + h * 9 + c) * N + ro;
        *(float4*)dst = make_float4(acc0[0], acc0[1], acc0[2], acc0[3]);
        *(float4*)(dst + 64) = make_float4(acc1[0], acc1[1], acc1[2], acc1[3]);
    }
}

// ---------------- K3b: finalize layer 1 + layer-2 features + fused layer-2 max ----------------
__global__ void k3b_final(const float* __restrict__ part1, const float* __restrict__ Wo,
                          const float* __restrict__ ao,
                          float4* __restrict__ rec2, float* __restrict__ f1b,
                          unsigned* __restrict__ amax) {
    __shared__ float sW[64];
    __shared__ float sa[4];
    int tid = threadIdx.x;
    if (tid < 64) sW[tid] = Wo[tid];
    if (tid < 4) sa[tid] = ao[tid];
    __syncthreads();
    int row = blockIdx.x * 256 + tid;
    float hv[32];
#pragma unroll
    for (int h = 0; h < NH; h++) {
        float s[9];
#pragma unroll
        for (int cc = 0; cc < 9; cc++) {
            float acc = 0.f;
#pragma unroll
            for (int js = 0; js < JS; js++)
                acc += part1[(size_t)(js * 36 + h * 9 + cc) * N + row];
            s[cc] = acc;
        }
        float inv = 1.f / s[8];
#pragma unroll
        for (int k = 0; k < FH; k++) {
            float o = s[k] * inv;
            hv[h * 8 + k] = (o > 0.f) ? o : expm1f(o);
        }
    }
    float h0 = 0.f, h1 = 0.f;
#pragma unroll
    for (int i = 0; i < 32; i++) {
        h0 = fmaf(hv[i], sW[i * 2 + 0], h0);
        h1 = fmaf(hv[i], sW[i * 2 + 1], h1);
    }
    float f1 = (h0 * sa[0] + h1 * sa[1]) * LOG2E;
    float f2 = (h0 * sa[2] + h1 * sa[3]) * LOG2E;
    rec2[row] = make_float4(__builtin_amdgcn_exp2f(f2), h0, h1,
                            __builtin_amdgcn_exp2f(ALPHA * f2));
    f1b[row] = f1;
    float vmax = f2;
    for (int off = 32; off > 0; off >>= 1) vmax = fmaxf(vmax, __shfl_xor(vmax, off, 64));
    if ((tid & 63) == 0) atomicMax(&amax[4], fenc(vmax));
}

// ---------------- K6: layer-2 attention partials — exp-factorized, no LDS ----------------
__global__ __launch_bounds__(256) void k6_attn2(
    const ull* __restrict__ mask, const float4* __restrict__ rec2,
    const float* __restrict__ f1b, const unsigned* __restrict__ amax,
    float* __restrict__ part2) {
    int tid = threadIdx.x;
    int lane = tid & 63;
    int wave = tid >> 6;
    int blk = blockIdx.x >> 2;
    int js = blockIdx.x & 3;
    int rbase = blk * 16 + wave * 4;
    const int JR = N / JS2;   // 2048
    int jbase = js * JR;

    float mb = fdec(amax[4]);
    float e1p[4], e1n[4];
#pragma unroll
    for (int i = 0; i < 4; i++) {
        float f1 = f1b[rbase + i];
        float v = f1 + mb, m = fmaxf(v, ALPHA * v);
        e1p[i] = __builtin_amdgcn_exp2f(f1 - m);
        e1n[i] = __builtin_amdgcn_exp2f(ALPHA * f1 - m);
    }
    float a0[4] = {0.f, 0.f, 0.f, 0.f};
    float a1[4] = {0.f, 0.f, 0.f, 0.f};
    float dd[4] = {0.f, 0.f, 0.f, 0.f};
    const ull* mr[4];
#pragma unroll
    for (int i = 0; i < 4; i++) mr[i] = mask + (size_t)(rbase + i) * NW;

    int wb = jbase >> 6;
#pragma unroll 4
    for (int s = 0; s < JR / 64; s++) {   // 32
        float4 q = rec2[jbase + s * 64 + lane];
#pragma unroll
        for (int i = 0; i < 4; i++) {
            ull mw = mr[i][wb + s];
            float w = fmaxf(e1p[i] * q.x, e1n[i] * q.w);
            w = ((mw >> lane) & 1ull) ? w : 0.f;
            a0[i] = fmaf(w, q.y, a0[i]);
            a1[i] = fmaf(w, q.z, a1[i]);
            dd[i] += w;
        }
    }
#pragma unroll
    for (int i = 0; i < 4; i++) {
        for (int off = 32; off > 0; off >>= 1) {
            a0[i] += __shfl_xor(a0[i], off, 64);
            a1[i] += __shfl_xor(a1[i], off, 64);
            dd[i] += __shfl_xor(dd[i], off, 64);
        }
    }
    if (lane == 0) {
#pragma unroll
        for (int i = 0; i < 4; i++) {
            int row = rbase + i;
            part2[(js * 3 + 0) * N + row] = a0[i];
            part2[(js * 3 + 1) * N + row] = a1[i];
            part2[(js * 3 + 2) * N + row] = dd[i];
        }
    }
}

// ---------------- K6b: finalize layer 2 + log_softmax ----------------
__global__ void k6b_final(const float* __restrict__ part2, float* __restrict__ out) {
    int row = blockIdx.x * 256 + threadIdx.x;
    float s0 = 0.f, s1 = 0.f, d = 0.f;
#pragma unroll
    for (int js = 0; js < JS2; js++) {
        s0 += part2[(js * 3 + 0) * N + row];
        s1 += part2[(js * 3 + 1) * N + row];
        d  += part2[(js * 3 + 2) * N + row];
    }
    float inv = 1.f / d;
    float e0 = s0 * inv, e1 = s1 * inv;
    e0 = (e0 > 0.f) ? e0 : expm1f(e0);
    e1 = (e1 > 0.f) ? e1 : expm1f(e1);
    float mx = fmaxf(e0, e1);
    float lse = mx + logf(expf(e0 - mx) + expf(e1 - mx));
    ((float2*)out)[row] = make_float2(e0 - lse, e1 - lse);
}

extern "C" void kernel_launch(void* const* d_in, const int* in_sizes, int n_in,
                              void* d_out, int out_size, void* d_ws, size_t ws_size,
                              hipStream_t stream) {
    const float* x   = (const float*)d_in[0];
    const int*   adj = (const int*)d_in[1];
    const float* Wh  = (const float*)d_in[2];
    const float* ah  = (const float*)d_in[3];
    const float* Wo  = (const float*)d_in[4];
    const float* ao  = (const float*)d_in[5];
    float* out = (float*)d_out;
    float* ws = (float*)d_ws;

    // workspace layout (float offsets)
    ull*      mask  = (ull*)ws;                       // 8 MB = 2097152 floats
    float2*   e2    = (float2*)(ws + 2097152);        // 4*N float2 = 65536 floats
    u16*      Bpk   = (u16*)(ws + 2162688);           // 1 MB = 262144 floats
    float*    f1a   = ws + 2424832;                   // 4*N
    float*    part1 = ws + 2457600;                   // 4*36*N = 1179648
    float4*   rec2  = (float4*)(ws + 3637248);        // N float4
    float*    f1b   = ws + 3670016;                   // N
    float*    part2 = ws + 3678208;                   // 12*N = 98304
    unsigned* amax  = (unsigned*)(ws + 3776512);      // 8 slots (0..3 heads, 4 layer2)

    k0_pack<<<N, 256, 0, stream>>>(adj, mask, amax);
    k1_feat<<<N / 64, 256, 0, stream>>>(x, Wh, ah, e2, Bpk, f1a, amax);
    k3_attn1<<<(N / 128) * JS * NH, 256, 0, stream>>>(mask, e2, (const uint4*)Bpk, f1a, amax, part1);
    k3b_final<<<N / 256, 256, 0, stream>>>(part1, Wo, ao, rec2, f1b, amax);
    k6_attn2<<<(N / 16) * JS2, 256, 0, stream>>>(mask, rec2, f1b, amax, part2);
    k6b_final<<<N / 256, 256, 0, stream>>>(part2, out);
}